// Round 1
// baseline (1457.511 us; speedup 1.0000x reference)
//
#include <hip/hip_runtime.h>
#include <math.h>

#define B_   256
#define L_   196
#define R_   1024
#define E_   1024
#define H_   512
#define G4R  4096   // 4*R
#define DIN  3072   // E + 2R

__device__ __forceinline__ float sigmoidf_(float x) {
    return 1.0f / (1.0f + __expf(-x));
}
__device__ __forceinline__ float tanhf_(float x) {
    float ax = fabsf(x);
    float t  = __expf(-2.0f * ax);
    float r  = (1.0f - t) / (1.0f + t);
    return copysignf(r, x);
}

// C[m,n] = sum_k A1[m,k]*W1[n,k] + sum_k A2[m,k]*W2[n,k] + bias1[n] (+ bias2[n])
// A row-major (M,K), W row-major (N,K). Tile 64x64, 256 threads, 4x4/thread, BK=16.
__global__ __launch_bounds__(256) void gemm2_bias(
    const float* __restrict__ A1, const float* __restrict__ W1, int K1,
    const float* __restrict__ A2, const float* __restrict__ W2, int K2,
    const float* __restrict__ bias1, const float* __restrict__ bias2,
    float* __restrict__ C, int N)
{
    __shared__ float As[16][64];
    __shared__ float Ws[16][64];
    const int t  = threadIdx.x;
    const int tx = t & 15, ty = t >> 4;
    const int mBase = blockIdx.x * 64;
    const int nBase = blockIdx.y * 64;
    const int lr = t >> 2;          // 0..63 (tile row)
    const int lk = (t & 3) * 4;     // 0,4,8,12 (k offset)

    float acc[4][4];
#pragma unroll
    for (int i = 0; i < 4; i++)
#pragma unroll
        for (int j = 0; j < 4; j++) acc[i][j] = 0.0f;

    for (int seg = 0; seg < 2; ++seg) {
        const int K = seg ? K2 : K1;
        if (K == 0) continue;
        const float* A = seg ? A2 : A1;
        const float* W = seg ? W2 : W1;
        const float* aPtr = A + (size_t)(mBase + lr) * K + lk;
        const float* wPtr = W + (size_t)(nBase + lr) * K + lk;

        float4 av = *(const float4*)(aPtr);
        float4 wv = *(const float4*)(wPtr);

        for (int k0 = 0; k0 < K; k0 += 16) {
            float4 avn, wvn;
            if (k0 + 16 < K) {                      // prefetch next tile
                avn = *(const float4*)(aPtr + k0 + 16);
                wvn = *(const float4*)(wPtr + k0 + 16);
            } else { avn = av; wvn = wv; }

            __syncthreads();
            As[lk + 0][lr] = av.x; As[lk + 1][lr] = av.y;
            As[lk + 2][lr] = av.z; As[lk + 3][lr] = av.w;
            Ws[lk + 0][lr] = wv.x; Ws[lk + 1][lr] = wv.y;
            Ws[lk + 2][lr] = wv.z; Ws[lk + 3][lr] = wv.w;
            __syncthreads();

#pragma unroll
            for (int k = 0; k < 16; k++) {
                float4 a = *(const float4*)&As[k][ty * 4];
                float4 b = *(const float4*)&Ws[k][tx * 4];
                acc[0][0] += a.x * b.x; acc[0][1] += a.x * b.y;
                acc[0][2] += a.x * b.z; acc[0][3] += a.x * b.w;
                acc[1][0] += a.y * b.x; acc[1][1] += a.y * b.y;
                acc[1][2] += a.y * b.z; acc[1][3] += a.y * b.w;
                acc[2][0] += a.z * b.x; acc[2][1] += a.z * b.y;
                acc[2][2] += a.z * b.z; acc[2][3] += a.z * b.w;
                acc[3][0] += a.w * b.x; acc[3][1] += a.w * b.y;
                acc[3][2] += a.w * b.z; acc[3][3] += a.w * b.w;
            }
            av = avn; wv = wvn;
        }
    }

#pragma unroll
    for (int i = 0; i < 4; i++) {
        int m = mBase + ty * 4 + i;
#pragma unroll
        for (int j = 0; j < 4; j++) {
            int n = nBase + tx * 4 + j;
            float v = acc[i][j] + bias1[n];
            if (bias2) v += bias2[n];
            C[(size_t)m * N + n] = v;
        }
    }
}

// gates (B,4R) + c_in (B,R) -> h_out, c_out (B,R); optional mirror of h.
__global__ __launch_bounds__(256) void lstm_cell(
    const float* __restrict__ gates, const float* __restrict__ c_in,
    float* __restrict__ h_out, float* __restrict__ c_out,
    float* __restrict__ h_out2)
{
    int e = blockIdx.x * 256 + threadIdx.x;   // e < B*R
    int b = e >> 10;
    int j = e & 1023;
    const float* g = gates + (size_t)b * G4R;
    float i_ = sigmoidf_(g[j]);
    float f_ = sigmoidf_(g[j + 1024]);
    float gg = tanhf_(g[j + 2048]);
    float o_ = sigmoidf_(g[j + 3072]);
    float c  = f_ * c_in[e] + i_ * gg;
    float h  = o_ * tanhf_(c);
    c_out[e] = c;
    h_out[e] = h;
    if (h_out2) h_out2[e] = h;
}

// dst(B,3072) = [s0 | s1 | s2], each 1024 wide, with per-source row stride.
__global__ __launch_bounds__(256) void concat3_1024(
    float* __restrict__ dst,
    const float* __restrict__ s0, int ld0,
    const float* __restrict__ s1, int ld1,
    const float* __restrict__ s2, int ld2)
{
    int e = blockIdx.x * 256 + threadIdx.x;   // e < B*3072
    int b = e / 3072;
    int c = e - b * 3072;
    int which = c >> 10, off = c & 1023;
    const float* s = (which == 0) ? s0 : (which == 1) ? s1 : s2;
    int ld = (which == 0) ? ld0 : (which == 1) ? ld1 : ld2;
    dst[e] = s[(size_t)b * ld + off];
}

// scores[b,l] = sum_h tanh(p[b,l,h] + att_h[b,h]) * Wa[h] + ba
__global__ __launch_bounds__(64) void attn_scores(
    const float* __restrict__ p_att,   // (B,L,H)
    const float* __restrict__ att_h,   // (B,H)
    const float* __restrict__ Wa,      // (H)
    const float* __restrict__ ba,      // scalar
    float* __restrict__ scores)        // (B,L)
{
    int l = blockIdx.x;
    int b = blockIdx.y;
    int lane = threadIdx.x;
    const float* p  = p_att + ((size_t)b * L_ + l) * H_;
    const float* ah = att_h + (size_t)b * H_;
    float sum = 0.0f;
#pragma unroll
    for (int i = 0; i < H_ / 64; i++) {
        int h = lane + i * 64;
        sum += tanhf_(p[h] + ah[h]) * Wa[h];
    }
    for (int off = 32; off; off >>= 1) sum += __shfl_down(sum, off);
    if (lane == 0) scores[(size_t)b * L_ + l] = sum + ba[0];
}

// w = softmax(scores, axis=1); w *= mask; w /= (sum(w)+1e-10)
__global__ __launch_bounds__(256) void attn_softmax(
    const float* __restrict__ scores, const float* __restrict__ mask,
    float* __restrict__ w)
{
    int b = blockIdx.x;
    int t = threadIdx.x;
    __shared__ float red[256];
    float v = (t < L_) ? scores[(size_t)b * L_ + t] : -1e30f;
    red[t] = v; __syncthreads();
    for (int s = 128; s; s >>= 1) {
        if (t < s) red[t] = fmaxf(red[t], red[t + s]);
        __syncthreads();
    }
    float mx = red[0]; __syncthreads();
    float e = (t < L_) ? __expf(v - mx) : 0.0f;
    red[t] = e; __syncthreads();
    for (int s = 128; s; s >>= 1) {
        if (t < s) red[t] += red[t + s];
        __syncthreads();
    }
    float denom = red[0]; __syncthreads();
    float wm = (t < L_) ? (e / denom) * mask[(size_t)b * L_ + t] : 0.0f;
    red[t] = wm; __syncthreads();
    for (int s = 128; s; s >>= 1) {
        if (t < s) red[t] += red[t + s];
        __syncthreads();
    }
    float denom2 = red[0] + 1e-10f;
    if (t < L_) w[(size_t)b * L_ + t] = wm / denom2;
}

// out[b,r] = sum_l w[b,l] * feats[b,l,r]
__global__ __launch_bounds__(256) void attn_wsum(
    const float* __restrict__ w,       // (B,L)
    const float* __restrict__ feats,   // (B,L,R)
    float* __restrict__ out)           // (B,R)
{
    int b = blockIdx.y;
    int r = blockIdx.x * 256 + threadIdx.x;
    __shared__ float ws[L_];
    for (int i = threadIdx.x; i < L_; i += 256)
        ws[i] = w[(size_t)b * L_ + i];
    __syncthreads();
    const float* f = feats + (size_t)b * L_ * R_ + r;
    float a0 = 0, a1 = 0, a2 = 0, a3 = 0;
    for (int l = 0; l < L_; l += 4) {
        a0 += ws[l + 0] * f[(size_t)(l + 0) * R_];
        a1 += ws[l + 1] * f[(size_t)(l + 1) * R_];
        a2 += ws[l + 2] * f[(size_t)(l + 2) * R_];
        a3 += ws[l + 3] * f[(size_t)(l + 3) * R_];
    }
    out[(size_t)b * R_ + r] = a0 + a1 + a2 + a3;
}

extern "C" void kernel_launch(void* const* d_in, const int* in_sizes, int n_in,
                              void* d_out, int out_size, void* d_ws, size_t ws_size,
                              hipStream_t stream)
{
    const float* xt         = (const float*)d_in[0];
    const float* fc_feats   = (const float*)d_in[1];
    const float* att_feats  = (const float*)d_in[2];
    const float* p_att      = (const float*)d_in[3];
    const float* mask       = (const float*)d_in[4];
    const float* att_feats1 = (const float*)d_in[5];
    const float* p_att1     = (const float*)d_in[6];
    const float* mask1      = (const float*)d_in[7];
    const float* state_h    = (const float*)d_in[8];
    const float* state_c    = (const float*)d_in[9];
    const float* Wih0 = (const float*)d_in[10];
    const float* Whh0 = (const float*)d_in[11];
    const float* bih0 = (const float*)d_in[12];
    const float* bhh0 = (const float*)d_in[13];
    const float* Wih1 = (const float*)d_in[14];
    const float* Whh1 = (const float*)d_in[15];
    const float* bih1 = (const float*)d_in[16];
    const float* bhh1 = (const float*)d_in[17];
    const float* WihL = (const float*)d_in[18];
    const float* WhhL = (const float*)d_in[19];
    const float* bihL = (const float*)d_in[20];
    const float* bhhL = (const float*)d_in[21];
    const float* a0_Wh = (const float*)d_in[22];
    const float* a0_bh = (const float*)d_in[23];
    const float* a0_Wa = (const float*)d_in[24];
    const float* a0_ba = (const float*)d_in[25];
    const float* a_Wh  = (const float*)d_in[26];
    const float* a_bh  = (const float*)d_in[27];
    const float* a_Wa  = (const float*)d_in[28];
    const float* a_ba  = (const float*)d_in[29];
    const float* a1_Wh = (const float*)d_in[30];
    const float* a1_bh = (const float*)d_in[31];
    const float* a1_Wa = (const float*)d_in[32];
    const float* a1_ba = (const float*)d_in[33];

    const size_t BR = (size_t)B_ * R_;
    float* out   = (float*)d_out;           // output (B,R)
    float* h0    = out + 1 * BR;            // new_h[0]
    float* h1    = out + 2 * BR;            // new_h[1]
    float* h2    = out + 3 * BR;            // new_h[2]
    float* c0    = out + 4 * BR;            // new_c[0]
    float* c1    = out + 5 * BR;            // new_c[1]
    float* c2    = out + 6 * BR;            // new_c[2]

    float* xbuf  = (float*)d_ws;                          // B*3072
    float* gates = xbuf + (size_t)B_ * DIN;               // B*4096
    float* atth  = gates + (size_t)B_ * G4R;              // B*H
    float* sc    = atth + (size_t)B_ * H_;                // B*L
    float* att0  = sc + (size_t)B_ * L_;                  // B*R
    float* attA  = att0 + BR;                             // B*R
    float* attB  = attA + BR;                             // B*R

    const float* prev_h = state_h + 2 * BR;

    dim3 gG(B_ / 64, G4R / 64);   // gates GEMM grid
    dim3 gA(B_ / 64, H_ / 64);    // att_h GEMM grid
    dim3 gS(L_, B_);              // scores grid
    dim3 gW(R_ / 256, B_);        // wsum grid

    // ---- stage 0: LSTM att0 ----
    concat3_1024<<<(B_ * DIN) / 256, 256, 0, stream>>>(xbuf, prev_h, R_, fc_feats, 3 * R_, xt, E_);
    gemm2_bias<<<gG, 256, 0, stream>>>(xbuf, Wih0, DIN, state_h, Whh0, R_, bih0, bhh0, gates, G4R);
    lstm_cell<<<(B_ * R_) / 256, 256, 0, stream>>>(gates, state_c, h0, c0, nullptr);

    // ---- attention 0 (feats1, params a0) ----
    gemm2_bias<<<gA, 256, 0, stream>>>(h0, a0_Wh, R_, nullptr, nullptr, 0, a0_bh, nullptr, atth, H_);
    attn_scores<<<gS, 64, 0, stream>>>(p_att1, atth, a0_Wa, a0_ba, sc);
    attn_softmax<<<B_, 256, 0, stream>>>(sc, mask1, sc);
    attn_wsum<<<gW, 256, 0, stream>>>(sc, att_feats1, att0);

    // ---- stage 1: LSTM att ----
    concat3_1024<<<(B_ * DIN) / 256, 256, 0, stream>>>(xbuf, prev_h, R_, att0, R_, xt, E_);
    gemm2_bias<<<gG, 256, 0, stream>>>(xbuf, Wih1, DIN, state_h + BR, Whh1, R_, bih1, bhh1, gates, G4R);
    lstm_cell<<<(B_ * R_) / 256, 256, 0, stream>>>(gates, state_c + BR, h1, c1, nullptr);

    // ---- attention a (feats, params a) -> attA ----
    gemm2_bias<<<gA, 256, 0, stream>>>(h1, a_Wh, R_, nullptr, nullptr, 0, a_bh, nullptr, atth, H_);
    attn_scores<<<gS, 64, 0, stream>>>(p_att, atth, a_Wa, a_ba, sc);
    attn_softmax<<<B_, 256, 0, stream>>>(sc, mask, sc);
    attn_wsum<<<gW, 256, 0, stream>>>(sc, att_feats, attA);

    // ---- attention a1 (feats1, params a1) -> attB ----
    gemm2_bias<<<gA, 256, 0, stream>>>(h1, a1_Wh, R_, nullptr, nullptr, 0, a1_bh, nullptr, atth, H_);
    attn_scores<<<gS, 64, 0, stream>>>(p_att1, atth, a1_Wa, a1_ba, sc);
    attn_softmax<<<B_, 256, 0, stream>>>(sc, mask1, sc);
    attn_wsum<<<gW, 256, 0, stream>>>(sc, att_feats1, attB);

    // ---- stage 2: LSTM lang ----
    concat3_1024<<<(B_ * DIN) / 256, 256, 0, stream>>>(xbuf, attA, R_, attB, R_, h1, R_);
    gemm2_bias<<<gG, 256, 0, stream>>>(xbuf, WihL, DIN, state_h + 2 * BR, WhhL, R_, bihL, bhhL, gates, G4R);
    lstm_cell<<<(B_ * R_) / 256, 256, 0, stream>>>(gates, state_c + 2 * BR, h2, c2, out);
}

// Round 2
// 1218.582 us; speedup vs baseline: 1.1961x; 1.1961x over previous
//
#include <hip/hip_runtime.h>
#include <math.h>

#define B_   256
#define L_   196
#define R_   1024
#define E_   1024
#define H_   512
#define G4R  4096   // 4*R
#define DIN  3072   // E + 2R

typedef short v4s __attribute__((ext_vector_type(4)));
typedef short v8s __attribute__((ext_vector_type(8)));
typedef float v4f __attribute__((ext_vector_type(4)));

__device__ __forceinline__ float sigmoidf_(float x) {
    return 1.0f / (1.0f + __expf(-x));
}
__device__ __forceinline__ float tanhf_(float x) {
    float ax = fabsf(x);
    float t  = __expf(-2.0f * ax);
    float r  = (1.0f - t) / (1.0f + t);
    return copysignf(r, x);
}

// split fp32 into two truncated bf16 parts: x ~= hi + lo (error ~2^-14 rel)
__device__ __forceinline__ void split2(float x, short& hi, short& lo) {
    unsigned u = __float_as_uint(x);
    hi = (short)(u >> 16);
    float r = x - __uint_as_float(u & 0xFFFF0000u);
    lo = (short)(__float_as_uint(r) >> 16);
}

// C[m,n] = sum_k A1[m,k]*W1[n,k] + sum_k A2[m,k]*W2[n,k] + bias1[n] (+bias2[n])
// Split-precision bf16 MFMA (3 mfma per frag pair): ~fp32 accuracy.
// Block = 256 threads = 4 waves in 2x2; wave tile = (MT/2) x (NT/2).
template<int MT, int NT>
__global__ __launch_bounds__(256) void gemm_mfma(
    const float* __restrict__ A1, const float* __restrict__ W1, int K1, int lda1,
    const float* __restrict__ A2, const float* __restrict__ W2, int K2, int lda2,
    const float* __restrict__ bias1, const float* __restrict__ bias2,
    float* __restrict__ C, int N)
{
    constexpr int FM  = MT / 32;            // m-frags per wave
    constexpr int FN  = NT / 32;            // n-frags per wave
    constexpr int ACH = (MT * 32) / 1024;   // float4 chunks per thread (A)
    constexpr int WCH = (NT * 32) / 1024;   // float4 chunks per thread (W)

    __shared__ alignas(16) short Ahi[MT][40];
    __shared__ alignas(16) short Alo[MT][40];
    __shared__ alignas(16) short Whi[NT][40];
    __shared__ alignas(16) short Wlo[NT][40];

    const int t     = threadIdx.x;
    const int lane  = t & 63;
    const int wave  = t >> 6;
    const int waveM = wave & 1;
    const int waveN = wave >> 1;
    const int l16   = lane & 15;
    const int quad  = lane >> 4;
    const int mBase = blockIdx.x * MT;
    const int nBase = blockIdx.y * NT;

    v4f acc[FM][FN] = {};

    for (int seg = 0; seg < 2; ++seg) {
        const int K = seg ? K2 : K1;
        if (K == 0) continue;
        const float* Ag  = seg ? A2 : A1;
        const float* Wg  = seg ? W2 : W1;
        const int    lda = seg ? lda2 : lda1;

        for (int k0 = 0; k0 < K; k0 += 32) {
            __syncthreads();
            // ---- stage A tile (MT x 32) with hi/lo split ----
            #pragma unroll
            for (int c = 0; c < ACH; ++c) {
                int flat = t * 4 + c * 1024;
                int row  = flat >> 5, k = flat & 31;
                float4 v = *(const float4*)(Ag + (size_t)(mBase + row) * lda + k0 + k);
                short h0, h1, h2, h3, l0, l1, l2, l3;
                split2(v.x, h0, l0); split2(v.y, h1, l1);
                split2(v.z, h2, l2); split2(v.w, h3, l3);
                v4s hv = { h0, h1, h2, h3 };
                v4s lv = { l0, l1, l2, l3 };
                *(v4s*)&Ahi[row][k] = hv;
                *(v4s*)&Alo[row][k] = lv;
            }
            // ---- stage W tile (NT x 32) with hi/lo split ----
            #pragma unroll
            for (int c = 0; c < WCH; ++c) {
                int flat = t * 4 + c * 1024;
                int row  = flat >> 5, k = flat & 31;
                float4 v = *(const float4*)(Wg + (size_t)(nBase + row) * K + k0 + k);
                short h0, h1, h2, h3, l0, l1, l2, l3;
                split2(v.x, h0, l0); split2(v.y, h1, l1);
                split2(v.z, h2, l2); split2(v.w, h3, l3);
                v4s hv = { h0, h1, h2, h3 };
                v4s lv = { l0, l1, l2, l3 };
                *(v4s*)&Whi[row][k] = hv;
                *(v4s*)&Wlo[row][k] = lv;
            }
            __syncthreads();

            // ---- fragments ----
            v8s ah[FM], al[FM], wh[FN], wl[FN];
            #pragma unroll
            for (int fi = 0; fi < FM; ++fi) {
                int r = waveM * (MT / 2) + fi * 16 + l16;
                ah[fi] = *(const v8s*)&Ahi[r][quad * 8];
                al[fi] = *(const v8s*)&Alo[r][quad * 8];
            }
            #pragma unroll
            for (int fj = 0; fj < FN; ++fj) {
                int r = waveN * (NT / 2) + fj * 16 + l16;
                wh[fj] = *(const v8s*)&Whi[r][quad * 8];
                wl[fj] = *(const v8s*)&Wlo[r][quad * 8];
            }

            // ---- 3-term split MFMA ----
            #pragma unroll
            for (int fi = 0; fi < FM; ++fi)
                #pragma unroll
                for (int fj = 0; fj < FN; ++fj) {
                    acc[fi][fj] = __builtin_amdgcn_mfma_f32_16x16x32_bf16(
                        al[fi], wh[fj], acc[fi][fj], 0, 0, 0);
                    acc[fi][fj] = __builtin_amdgcn_mfma_f32_16x16x32_bf16(
                        ah[fi], wl[fj], acc[fi][fj], 0, 0, 0);
                    acc[fi][fj] = __builtin_amdgcn_mfma_f32_16x16x32_bf16(
                        ah[fi], wh[fj], acc[fi][fj], 0, 0, 0);
                }
        }
    }

    // ---- epilogue: C/D layout col=lane&15, row=quad*4+reg ----
    #pragma unroll
    for (int fj = 0; fj < FN; ++fj) {
        int n = nBase + waveN * (NT / 2) + fj * 16 + l16;
        float bb = bias1[n] + (bias2 ? bias2[n] : 0.0f);
        #pragma unroll
        for (int fi = 0; fi < FM; ++fi) {
            int m0 = mBase + waveM * (MT / 2) + fi * 16 + quad * 4;
            #pragma unroll
            for (int r = 0; r < 4; ++r)
                C[(size_t)(m0 + r) * N + n] = acc[fi][fj][r] + bb;
        }
    }
}

// gates (B,4R) + c_in (B,R) -> h_out, c_out (B,R); optional mirror of h.
__global__ __launch_bounds__(256) void lstm_cell(
    const float* __restrict__ gates, const float* __restrict__ c_in,
    float* __restrict__ h_out, float* __restrict__ c_out,
    float* __restrict__ h_out2)
{
    int e = blockIdx.x * 256 + threadIdx.x;   // e < B*R
    int b = e >> 10;
    int j = e & 1023;
    const float* g = gates + (size_t)b * G4R;
    float i_ = sigmoidf_(g[j]);
    float f_ = sigmoidf_(g[j + 1024]);
    float gg = tanhf_(g[j + 2048]);
    float o_ = sigmoidf_(g[j + 3072]);
    float c  = f_ * c_in[e] + i_ * gg;
    float h  = o_ * tanhf_(c);
    c_out[e] = c;
    h_out[e] = h;
    if (h_out2) h_out2[e] = h;
}

// dst(B,3072) = [s0 | s1 | s2], each 1024 wide, with per-source row stride.
__global__ __launch_bounds__(256) void concat3_1024(
    float* __restrict__ dst,
    const float* __restrict__ s0, int ld0,
    const float* __restrict__ s1, int ld1,
    const float* __restrict__ s2, int ld2)
{
    int e = blockIdx.x * 256 + threadIdx.x;   // e < B*3072
    int b = e / 3072;
    int c = e - b * 3072;
    int which = c >> 10, off = c & 1023;
    const float* s = (which == 0) ? s0 : (which == 1) ? s1 : s2;
    int ld = (which == 0) ? ld0 : (which == 1) ? ld1 : ld2;
    dst[e] = s[(size_t)b * ld + off];
}

// scores[b,l] = sum_h tanh(p[b,l,h] + att_h[b,h]) * Wa[h] + ba
__global__ __launch_bounds__(64) void attn_scores(
    const float* __restrict__ p_att,   // (B,L,H)
    const float* __restrict__ att_h,   // (B,H)
    const float* __restrict__ Wa,      // (H)
    const float* __restrict__ ba,      // scalar
    float* __restrict__ scores)        // (B,L)
{
    int l = blockIdx.x;
    int b = blockIdx.y;
    int lane = threadIdx.x;
    const float* p  = p_att + ((size_t)b * L_ + l) * H_;
    const float* ah = att_h + (size_t)b * H_;
    float sum = 0.0f;
#pragma unroll
    for (int i = 0; i < H_ / 64; i++) {
        int h = lane + i * 64;
        sum += tanhf_(p[h] + ah[h]) * Wa[h];
    }
    for (int off = 32; off; off >>= 1) sum += __shfl_down(sum, off);
    if (lane == 0) scores[(size_t)b * L_ + l] = sum + ba[0];
}

// w = softmax(scores, axis=1); w *= mask; w /= (sum(w)+1e-10)
__global__ __launch_bounds__(256) void attn_softmax(
    const float* __restrict__ scores, const float* __restrict__ mask,
    float* __restrict__ w)
{
    int b = blockIdx.x;
    int t = threadIdx.x;
    __shared__ float red[256];
    float v = (t < L_) ? scores[(size_t)b * L_ + t] : -1e30f;
    red[t] = v; __syncthreads();
    for (int s = 128; s; s >>= 1) {
        if (t < s) red[t] = fmaxf(red[t], red[t + s]);
        __syncthreads();
    }
    float mx = red[0]; __syncthreads();
    float e = (t < L_) ? __expf(v - mx) : 0.0f;
    red[t] = e; __syncthreads();
    for (int s = 128; s; s >>= 1) {
        if (t < s) red[t] += red[t + s];
        __syncthreads();
    }
    float denom = red[0]; __syncthreads();
    float wm = (t < L_) ? (e / denom) * mask[(size_t)b * L_ + t] : 0.0f;
    red[t] = wm; __syncthreads();
    for (int s = 128; s; s >>= 1) {
        if (t < s) red[t] += red[t + s];
        __syncthreads();
    }
    float denom2 = red[0] + 1e-10f;
    if (t < L_) w[(size_t)b * L_ + t] = wm / denom2;
}

// out[b,r] = sum_l w[b,l] * feats[b,l,r]
__global__ __launch_bounds__(256) void attn_wsum(
    const float* __restrict__ w,       // (B,L)
    const float* __restrict__ feats,   // (B,L,R)
    float* __restrict__ out)           // (B,R)
{
    int b = blockIdx.y;
    int r = blockIdx.x * 256 + threadIdx.x;
    __shared__ float ws[L_];
    for (int i = threadIdx.x; i < L_; i += 256)
        ws[i] = w[(size_t)b * L_ + i];
    __syncthreads();
    const float* f = feats + (size_t)b * L_ * R_ + r;
    float a0 = 0, a1 = 0, a2 = 0, a3 = 0;
    for (int l = 0; l < L_; l += 4) {
        a0 += ws[l + 0] * f[(size_t)(l + 0) * R_];
        a1 += ws[l + 1] * f[(size_t)(l + 1) * R_];
        a2 += ws[l + 2] * f[(size_t)(l + 2) * R_];
        a3 += ws[l + 3] * f[(size_t)(l + 3) * R_];
    }
    out[(size_t)b * R_ + r] = a0 + a1 + a2 + a3;
}

extern "C" void kernel_launch(void* const* d_in, const int* in_sizes, int n_in,
                              void* d_out, int out_size, void* d_ws, size_t ws_size,
                              hipStream_t stream)
{
    const float* xt         = (const float*)d_in[0];
    const float* fc_feats   = (const float*)d_in[1];
    const float* att_feats  = (const float*)d_in[2];
    const float* p_att      = (const float*)d_in[3];
    const float* mask       = (const float*)d_in[4];
    const float* att_feats1 = (const float*)d_in[5];
    const float* p_att1     = (const float*)d_in[6];
    const float* mask1      = (const float*)d_in[7];
    const float* state_h    = (const float*)d_in[8];
    const float* state_c    = (const float*)d_in[9];
    const float* Wih0 = (const float*)d_in[10];
    const float* Whh0 = (const float*)d_in[11];
    const float* bih0 = (const float*)d_in[12];
    const float* bhh0 = (const float*)d_in[13];
    const float* Wih1 = (const float*)d_in[14];
    const float* Whh1 = (const float*)d_in[15];
    const float* bih1 = (const float*)d_in[16];
    const float* bhh1 = (const float*)d_in[17];
    const float* WihL = (const float*)d_in[18];
    const float* WhhL = (const float*)d_in[19];
    const float* bihL = (const float*)d_in[20];
    const float* bhhL = (const float*)d_in[21];
    const float* a0_Wh = (const float*)d_in[22];
    const float* a0_bh = (const float*)d_in[23];
    const float* a0_Wa = (const float*)d_in[24];
    const float* a0_ba = (const float*)d_in[25];
    const float* a_Wh  = (const float*)d_in[26];
    const float* a_bh  = (const float*)d_in[27];
    const float* a_Wa  = (const float*)d_in[28];
    const float* a_ba  = (const float*)d_in[29];
    const float* a1_Wh = (const float*)d_in[30];
    const float* a1_bh = (const float*)d_in[31];
    const float* a1_Wa = (const float*)d_in[32];
    const float* a1_ba = (const float*)d_in[33];

    const size_t BR = (size_t)B_ * R_;
    float* out   = (float*)d_out;           // output (B,R)
    float* h0    = out + 1 * BR;            // new_h[0]
    float* h1    = out + 2 * BR;            // new_h[1]
    float* h2    = out + 3 * BR;            // new_h[2]
    float* c0    = out + 4 * BR;            // new_c[0]
    float* c1    = out + 5 * BR;            // new_c[1]
    float* c2    = out + 6 * BR;            // new_c[2]

    float* xbuf  = (float*)d_ws;                          // B*3072
    float* gates = xbuf + (size_t)B_ * DIN;               // B*4096
    float* atth  = gates + (size_t)B_ * G4R;              // B*H
    float* sc    = atth + (size_t)B_ * H_;                // B*L
    float* att0  = sc + (size_t)B_ * L_;                  // B*R
    float* attA  = att0 + BR;                             // B*R
    float* attB  = attA + BR;                             // B*R

    const float* prev_h = state_h + 2 * BR;

    dim3 gG(B_ / 64, G4R / 64);   // gates MFMA grid: 4 x 64
    dim3 gA(B_ / 32, H_ / 32);    // att_h MFMA grid: 8 x 16
    dim3 gS(L_, B_);              // scores grid
    dim3 gW(R_ / 256, B_);        // wsum grid

    // ---- stage 0: LSTM att0 ----
    concat3_1024<<<(B_ * DIN) / 256, 256, 0, stream>>>(xbuf, prev_h, R_, fc_feats, 3 * R_, xt, E_);
    gemm_mfma<64, 64><<<gG, 256, 0, stream>>>(xbuf, Wih0, DIN, DIN,
                                              state_h, Whh0, R_, R_,
                                              bih0, bhh0, gates, G4R);
    lstm_cell<<<(B_ * R_) / 256, 256, 0, stream>>>(gates, state_c, h0, c0, nullptr);

    // ---- attention 0 (feats1, params a0) ----
    gemm_mfma<32, 32><<<gA, 256, 0, stream>>>(h0, a0_Wh, R_, R_,
                                              nullptr, nullptr, 0, 0,
                                              a0_bh, nullptr, atth, H_);
    attn_scores<<<gS, 64, 0, stream>>>(p_att1, atth, a0_Wa, a0_ba, sc);
    attn_softmax<<<B_, 256, 0, stream>>>(sc, mask1, sc);
    attn_wsum<<<gW, 256, 0, stream>>>(sc, att_feats1, att0);

    // ---- stage 1: LSTM att ----
    concat3_1024<<<(B_ * DIN) / 256, 256, 0, stream>>>(xbuf, prev_h, R_, att0, R_, xt, E_);
    gemm_mfma<64, 64><<<gG, 256, 0, stream>>>(xbuf, Wih1, DIN, DIN,
                                              state_h + BR, Whh1, R_, R_,
                                              bih1, bhh1, gates, G4R);
    lstm_cell<<<(B_ * R_) / 256, 256, 0, stream>>>(gates, state_c + BR, h1, c1, nullptr);

    // ---- attention a (feats, params a) -> attA ----
    gemm_mfma<32, 32><<<gA, 256, 0, stream>>>(h1, a_Wh, R_, R_,
                                              nullptr, nullptr, 0, 0,
                                              a_bh, nullptr, atth, H_);
    attn_scores<<<gS, 64, 0, stream>>>(p_att, atth, a_Wa, a_ba, sc);
    attn_softmax<<<B_, 256, 0, stream>>>(sc, mask, sc);
    attn_wsum<<<gW, 256, 0, stream>>>(sc, att_feats, attA);

    // ---- attention a1 (feats1, params a1) -> attB ----
    gemm_mfma<32, 32><<<gA, 256, 0, stream>>>(h1, a1_Wh, R_, R_,
                                              nullptr, nullptr, 0, 0,
                                              a1_bh, nullptr, atth, H_);
    attn_scores<<<gS, 64, 0, stream>>>(p_att1, atth, a1_Wa, a1_ba, sc);
    attn_softmax<<<B_, 256, 0, stream>>>(sc, mask1, sc);
    attn_wsum<<<gW, 256, 0, stream>>>(sc, att_feats1, attB);

    // ---- stage 2: LSTM lang ----
    concat3_1024<<<(B_ * DIN) / 256, 256, 0, stream>>>(xbuf, attA, R_, attB, R_, h1, R_);
    gemm_mfma<64, 64><<<gG, 256, 0, stream>>>(xbuf, WihL, DIN, DIN,
                                              state_h + 2 * BR, WhhL, R_, R_,
                                              bihL, bhhL, gates, G4R);
    lstm_cell<<<(B_ * R_) / 256, 256, 0, stream>>>(gates, state_c + 2 * BR, h2, c2, out);
}